// Round 3
// baseline (5994.799 us; speedup 1.0000x reference)
//
#include <hip/hip_runtime.h>
#include <hip/hip_bf16.h>

#define T_STEPS 256
#define BATCH   64
#define DIM_I   256
#define DIM_H   256
#define NBR     8
#define K_DIM   512
#define F_DIM   1024

typedef __attribute__((ext_vector_type(8))) short short8;
typedef __attribute__((ext_vector_type(4))) float floatx4;

__device__ __forceinline__ float sigmoid_fast(float x) {
    return 1.0f / (1.0f + __expf(-x));
}
__device__ __forceinline__ float tanh_fast(float x) {
    return 1.0f - 2.0f / (__expf(2.0f * x) + 1.0f);
}
// fp32 -> bf16 bits, round-to-nearest-even (finite inputs only)
__device__ __forceinline__ short f2bf(float f) {
    unsigned u = __float_as_uint(f);
    u += 0x7FFFu + ((u >> 16) & 1u);
    return (short)(u >> 16);
}

// ---------------------------------------------------------------------------
// Wt layout (B-fragment order, bf16):
//   fragment F = ((n*16 + kt)*8 + w)*8 + cc*4 + g      (kt: K-tile of 32, w: wave,
//   element    = Wt[F*512 + lane*8 + jj]                cc: 16-col chunk, g: gate)
//   holds W[n][k = kt*32 + (lane>>4)*8 + jj][f = g*256 + w*32 + cc*16 + (lane&15)]
// One-time prep: 16 MB fp32 read -> 8 MB bf16 write, fully coalesced writes.
// ---------------------------------------------------------------------------
__global__ void __launch_bounds__(256)
prep_kernel(const float* __restrict__ W, short* __restrict__ Wt) {
    int G    = blockIdx.x * 256 + threadIdx.x;   // 524288 total
    int lane = G & 63;
    int g    = (G >> 6) & 3;
    int cc   = (G >> 8) & 1;
    int w    = (G >> 9) & 7;
    int kt   = (G >> 12) & 15;
    int n    = (G >> 16) & 7;
    int k0   = kt * 32 + (lane >> 4) * 8;
    int f    = g * 256 + w * 32 + cc * 16 + (lane & 15);
    const float* src = W + ((size_t)(n * K_DIM + k0)) * F_DIM + f;
    short8 v;
#pragma unroll
    for (int jj = 0; jj < 8; ++jj) v[jj] = f2bf(src[(size_t)jj * F_DIM]);
    *reinterpret_cast<short8*>(Wt + (size_t)G * 8) = v;
}

// Stage x[t] rows r0..r0+15 (fp32) into A_frag k-tiles 0..7 as bf16, fragment
// order with XOR-swizzle (physical fragment p = logical ^ kt) for bank spread.
__device__ __forceinline__ void stage_x(const float* __restrict__ x,
                                        short* __restrict__ A_frag,
                                        int tid, int r0, int t) {
    int row = tid >> 5;          // 0..15
    int k0  = (tid & 31) * 8;    // 0..248
    const float4* px = reinterpret_cast<const float4*>(
        x + ((size_t)t * BATCH + r0 + row) * DIM_I + k0);
    float4 a0 = px[0];
    float4 a1 = px[1];
    int kt = k0 >> 5;
    int q  = (k0 >> 3) & 3;
    int p  = (q * 16 + row) ^ kt;
    short8 v;
    v[0] = f2bf(a0.x); v[1] = f2bf(a0.y); v[2] = f2bf(a0.z); v[3] = f2bf(a0.w);
    v[4] = f2bf(a1.x); v[5] = f2bf(a1.y); v[6] = f2bf(a1.z); v[7] = f2bf(a1.w);
    *reinterpret_cast<short8*>(&A_frag[(kt * 64 + p) * 8]) = v;
}

// Grid: 32 blocks x 512 threads (8 waves). Block = (branch n = bid&7,
// batch rows r0..r0+15). Owns the full recurrence for its 16 chains:
// no inter-block synchronization at all. h lives in LDS (A_frag k-tiles 8..15).
// Wave w computes z-cols for H-cols [w*32, w*32+32), all 4 gates (lane-local
// epilogue via MFMA C/D layout).
__global__ void __launch_bounds__(512)
durlm_kernel(const float* __restrict__ x,       // [T,B,I] fp32
             const int* __restrict__ dur,       // [T,B]
             const float* __restrict__ bias_i,  // [N,4H] fp32
             const float* __restrict__ bias_h,  // [N,4H] fp32
             float* __restrict__ out,           // [T,N,B,H] fp32
             const short* __restrict__ Wt)      // [8 MB] pre-swizzled bf16
{
    __shared__ short A_frag[16 * 64 * 8];   // 16 KB: kt 0..7 = x_t, 8..15 = h_t

    const int tid  = threadIdx.x;
    const int lane = tid & 63;
    const int wv   = tid >> 6;          // wave 0..7 -> H-cols [wv*32, wv*32+32)
    const int bid  = blockIdx.x;
    const int n    = bid & 7;           // branch (XCD-affine: bid%8)
    const int r0   = (bid >> 3) * 16;   // batch row group
    const int l15  = lane & 15;
    const int quad = lane >> 4;

    // per-lane gate biases
    float bias[2][4];
#pragma unroll
    for (int cc = 0; cc < 2; ++cc)
#pragma unroll
        for (int g = 0; g < 4; ++g) {
            int f = g * 256 + wv * 32 + cc * 16 + l15;
            bias[cc][g] = bias_i[n * F_DIM + f] + bias_h[n * F_DIM + f];
        }

    // stage x_0; zero h_0 region (shorts [4096, 8192))
    stage_x(x, A_frag, tid, r0, 0);
    *reinterpret_cast<short8*>(&A_frag[4096 + tid * 8]) = (short8)0;
    __syncthreads();

    float c_state[2][4] = {{0.f, 0.f, 0.f, 0.f}, {0.f, 0.f, 0.f, 0.f}};

    // W base for (n, wv, kt=0, cc=0, g=0), this lane
    const short* wbase = Wt + ((size_t)((n * 16) * 8 + wv)) * 8 * 512 + lane * 8;

    for (int t = 0; t < T_STEPS; ++t) {
        floatx4 acc[2][4];
#pragma unroll
        for (int cc = 0; cc < 2; ++cc)
#pragma unroll
            for (int g = 0; g < 4; ++g) acc[cc][g] = (floatx4){0.f, 0.f, 0.f, 0.f};

        const short* wp = wbase;
#pragma unroll
        for (int kt = 0; kt < 16; ++kt) {
            short8 a = *reinterpret_cast<const short8*>(
                &A_frag[(kt * 64 + (lane ^ (kt & 7))) * 8]);
#pragma unroll
            for (int cc = 0; cc < 2; ++cc)
#pragma unroll
                for (int g = 0; g < 4; ++g) {
                    short8 b = *reinterpret_cast<const short8*>(wp + (cc * 4 + g) * 512);
                    acc[cc][g] = __builtin_amdgcn_mfma_f32_16x16x32_bf16(
                        a, b, acc[cc][g], 0, 0, 0);
                }
            wp += 8 * 8 * 512;   // next k-tile
        }
        __syncthreads();   // all waves done reading A_frag

        int dvals[4];
#pragma unroll
        for (int r = 0; r < 4; ++r) dvals[r] = dur[t * BATCH + r0 + quad * 4 + r];

#pragma unroll
        for (int cc = 0; cc < 2; ++cc) {
            int j  = wv * 32 + cc * 16 + l15;        // H-col
            int kt = 8 + wv;                         // h k-tile (j>>5 == wv)
            int q  = cc * 2 + (l15 >> 3);            // B/A-fragment quad from k
#pragma unroll
            for (int r = 0; r < 4; ++r) {
                int row = quad * 4 + r;
                bool freeze = n > (dvals[r] >> 3);
                float zi = acc[cc][0][r] + bias[cc][0];
                float zf = acc[cc][1][r] + bias[cc][1];
                float zo = acc[cc][2][r] + bias[cc][2];
                float zg = acc[cc][3][r] + bias[cc][3];
                float ig = sigmoid_fast(zi);
                float fg = sigmoid_fast(zf);
                float og = sigmoid_fast(zo);
                float gg = tanh_fast(zg);
                float cn = freeze ? c_state[cc][r] : fg * c_state[cc][r] + ig * gg;
                c_state[cc][r] = cn;
                float hv = og * tanh_fast(cn);
                __builtin_nontemporal_store(
                    hv, &out[(((size_t)t * NBR + n) * BATCH + r0 + row) * DIM_H + j]);
                // h -> A_frag (fragment order + swizzle) for next step's MFMA
                int p = (q * 16 + row) ^ (kt & 7);
                A_frag[(kt * 64 + p) * 8 + (j & 7)] = f2bf(hv);
            }
        }
        if (t + 1 < T_STEPS) stage_x(x, A_frag, tid, r0, t + 1);
        __syncthreads();   // A_frag ready for next step
    }
}

extern "C" void kernel_launch(void* const* d_in, const int* in_sizes, int n_in,
                              void* d_out, int out_size, void* d_ws, size_t ws_size,
                              hipStream_t stream) {
    const float* x      = (const float*)d_in[0];
    const int*   durp   = (const int*)d_in[1];
    const float* weight = (const float*)d_in[2];
    const float* bias_i = (const float*)d_in[3];
    const float* bias_h = (const float*)d_in[4];
    float* out = (float*)d_out;

    short* Wt = (short*)d_ws;   // 8 MB pre-swizzled bf16 weights

    prep_kernel<<<2048, 256, 0, stream>>>(weight, Wt);
    durlm_kernel<<<32, 512, 0, stream>>>(x, durp, bias_i, bias_h, out, Wt);
}